// Round 4
// baseline (436.555 us; speedup 1.0000x reference)
//
#include <hip/hip_runtime.h>

// Problem constants
constexpr int BB = 1024;   // batch
constexpr int GG = 2000;   // genes
constexpr int SS = 32;     // per-gene width
constexpr int K1 = 4096, K2 = 2048, K3 = 1024;

constexpr int BH = BB * 64;               // 65536 floats

// workspace layout (floats)
constexpr int Y1P_OFF = 0;                // 4 split-K slabs
constexpr int Y2P_OFF = 4 * BH;           // 2 slabs
constexpr int Y3P_OFF = 6 * BH;           // 1 slab
constexpr int HP_OFF  = 7 * BH;           // 63 fc0 partial chunks [c][row][n]

constexpr int NCH       = 63;             // ceil(2000/32) gene chunks
constexpr int RPB       = 16;             // batch rows per gene block
constexpr int NGENE_BLK = NCH * (BB / RPB);   // 63*64 = 4032
constexpr int NGEMM_BLK = 224;            // 128 (Y1) + 64 (Y2) + 32 (Y3)
constexpr int KCH       = 1024;           // split-K chunk (outer)

__global__ __launch_bounds__(256, 8) void k1_gene_fc0_zgemm(
    const float* __restrict__ x,  const float* __restrict__ z1,
    const float* __restrict__ z2, const float* __restrict__ z3,
    const float* __restrict__ Wg, const float* __restrict__ bg,
    const float* __restrict__ W0,
    const float* __restrict__ W1, const float* __restrict__ W2,
    const float* __restrict__ W3, float* __restrict__ ws)
{
    __shared__ float lds[4608];           // 18 KB union: gene part[4096]+gS[512] / gemm zt+wt
    const int bid = blockIdx.x;
    const int t   = threadIdx.x;

    if (bid >= NGEMM_BLK) {
        // ---------- gene block: 16 rows x 32 genes, fused fc0 partial ----------
        const int gid   = bid - NGEMM_BLK;         // 0..4031
        const int chunk = gid % NCH;
        const int bgrp  = gid / NCH;               // 0..63
        const int g0    = chunk * 32;
        const int b0    = bgrp * RPB;
        const int gene  = t >> 3;                  // 0..31
        const int sub   = t & 7;                   // 0..7
        const int g     = g0 + gene;
        const bool gv   = (g < GG);

        float4 wg4 = make_float4(0.f, 0.f, 0.f, 0.f);
        if (gv) wg4 = ((const float4*)Wg)[g * 8 + sub];

        const float* xp = gv ? (x + (size_t)b0 * (GG * SS) + (size_t)g * SS + sub * 4)
                             : x;  // dummy for invalid genes; wg4==0 forces p=0

        float* part = lds;                         // [16][32][8] raw lane partials
        float* gS   = lds + 4096;                  // [16][32] relu'd gene values

        // phase 1: stream x, store raw per-lane partials (no cross-lane deps)
        #pragma unroll
        for (int ii = 0; ii < RPB; ii += 8) {
            float4 xr[8];
            #pragma unroll
            for (int j = 0; j < 8; ++j)
                xr[j] = *(const float4*)(xp + (size_t)(ii + j) * (GG * SS));
            #pragma unroll
            for (int j = 0; j < 8; ++j) {
                float p = (xr[j].x * wg4.x + xr[j].y * wg4.y)
                        + (xr[j].z * wg4.z + xr[j].w * wg4.w);
                part[(ii + j) * 256 + t] = p;
            }
        }
        __syncthreads();

        // phase 2: reduce 8 subs -> relu(gene); 512 (row,gene) pairs
        #pragma unroll
        for (int p = t; p < RPB * 32; p += 256) {
            const float4 a = *(const float4*)&part[p * 8];
            const float4 b = *(const float4*)&part[p * 8 + 4];
            float s = ((a.x + a.y) + (a.z + a.w)) + ((b.x + b.y) + (b.z + b.w));
            const int gg = g0 + (p & 31);
            const float bias = (gg < GG) ? bg[gg] : 0.f;
            gS[p] = fmaxf(s + bias, 0.f);
        }
        __syncthreads();

        // phase 3: fc0 partial hp[m][n] = sum_j gS[m][j] * W0[g0+j][n]
        const int n = t & 63;
        const int w = t >> 6;                      // rows w*4 .. w*4+3
        float acc0 = 0.f, acc1 = 0.f, acc2 = 0.f, acc3 = 0.f;
        const float* gSw = gS + (w * 4) * 32;
        #pragma unroll 8
        for (int j = 0; j < 32; ++j) {
            int gj = g0 + j; if (gj >= GG) gj = GG - 1;    // safe; gS row is 0 there
            const float w0v = W0[(size_t)gj * 64 + n];     // L1-hot, coalesced
            acc0 = fmaf(gSw[j],      w0v, acc0);
            acc1 = fmaf(gSw[32 + j], w0v, acc1);
            acc2 = fmaf(gSw[64 + j], w0v, acc2);
            acc3 = fmaf(gSw[96 + j], w0v, acc3);
        }
        float* hp = ws + HP_OFF + (size_t)chunk * BH + (size_t)b0 * 64;
        hp[(size_t)(w * 4 + 0) * 64 + n] = acc0;
        hp[(size_t)(w * 4 + 1) * 64 + n] = acc1;
        hp[(size_t)(w * 4 + 2) * 64 + n] = acc2;
        hp[(size_t)(w * 4 + 3) * 64 + n] = acc3;
    } else {
        // ---------- z-GEMM block: 32m x 64n tile, K-chunk 32, padded LDS ----------
        const int id = bid;                        // 0..223
        const float* z; const float* W; int K; int mt; int kslab; float* ys;
        if (id < 128)      { z = z1; W = W1; K = K1; mt = id >> 2; kslab = id & 3;
                             ys = ws + Y1P_OFF + (size_t)kslab * BH; }
        else if (id < 192) { int l = id - 128; z = z2; W = W2; K = K2; mt = l >> 1; kslab = l & 1;
                             ys = ws + Y2P_OFF + (size_t)kslab * BH; }
        else               { int l = id - 192; z = z3; W = W3; K = K3; mt = l; kslab = 0;
                             ys = ws + Y3P_OFF; }

        const int m0    = mt * 32;
        const int kbase = kslab * KCH;
        const int n2    = t & 31;                  // owns cols n2*2, n2*2+1
        const int mq    = t >> 5;                  // owns rows mq*4 .. +3 (0..7)
        float* zt = lds;                           // [32][36] padded, 4.6 KB
        float* wt = lds + 32 * 36;                 // [32][68] padded, 8.7 KB

        float2 acc[4];
        #pragma unroll
        for (int j = 0; j < 4; ++j) acc[j] = make_float2(0.f, 0.f);

        const int zr = t >> 3, zc = (t & 7) * 4;   // z stage: 32 rows x 8 f4
        for (int kc = 0; kc < KCH / 32; ++kc) {
            const int k0 = kbase + kc * 32;
            *(float4*)&zt[zr * 36 + zc] =
                *(const float4*)&z[(size_t)(m0 + zr) * K + k0 + zc];
            #pragma unroll
            for (int r = 0; r < 2; ++r) {
                const int idx = t + r * 256;       // 0..511
                const int row = idx >> 4;
                const int c4  = (idx & 15) * 4;
                *(float4*)&wt[row * 68 + c4] =
                    *(const float4*)&W[(size_t)(k0 + row) * 64 + c4];
            }
            __syncthreads();
            #pragma unroll
            for (int kk = 0; kk < 32; kk += 4) {
                const float2 wv0 = *(const float2*)&wt[(kk + 0) * 68 + n2 * 2];
                const float2 wv1 = *(const float2*)&wt[(kk + 1) * 68 + n2 * 2];
                const float2 wv2 = *(const float2*)&wt[(kk + 2) * 68 + n2 * 2];
                const float2 wv3 = *(const float2*)&wt[(kk + 3) * 68 + n2 * 2];
                #pragma unroll
                for (int j = 0; j < 4; ++j) {
                    const float4 zj = *(const float4*)&zt[(mq * 4 + j) * 36 + kk];
                    acc[j].x = fmaf(zj.x, wv0.x, acc[j].x); acc[j].y = fmaf(zj.x, wv0.y, acc[j].y);
                    acc[j].x = fmaf(zj.y, wv1.x, acc[j].x); acc[j].y = fmaf(zj.y, wv1.y, acc[j].y);
                    acc[j].x = fmaf(zj.z, wv2.x, acc[j].x); acc[j].y = fmaf(zj.z, wv2.y, acc[j].y);
                    acc[j].x = fmaf(zj.w, wv3.x, acc[j].x); acc[j].y = fmaf(zj.w, wv3.y, acc[j].y);
                }
            }
            __syncthreads();
        }
        #pragma unroll
        for (int j = 0; j < 4; ++j)
            *(float2*)&ys[(size_t)(m0 + mq * 4 + j) * 64 + n2 * 2] = acc[j];
    }
}

__global__ __launch_bounds__(256, 4) void k2_combine_mlp(
    const float* __restrict__ ws,
    const float* __restrict__ b0v,
    const float* __restrict__ b1v, const float* __restrict__ b2v,
    const float* __restrict__ b3v,
    const float* __restrict__ w1v, const float* __restrict__ w2v,
    const float* __restrict__ w3v,
    const float* __restrict__ fW1, const float* __restrict__ fb1,
    const float* __restrict__ fW2, const float* __restrict__ fb2,
    const float* __restrict__ fW3, const float* __restrict__ fb3,
    float* __restrict__ out)
{
    const float* Y1p = ws + Y1P_OFF;
    const float* Y2p = ws + Y2P_OFF;
    const float* Y3p = ws + Y3P_OFF;

    const int t   = threadIdx.x;
    const int n   = t & 63;
    const int w   = t >> 6;
    const int row = blockIdx.x * 4 + w;
    const int rn  = row * 64 + n;

    // ---- reduce fc0 partials over 63 gene chunks ----
    float h = 0.f;
    const float* hp = ws + HP_OFF + rn;
    #pragma unroll 9
    for (int c = 0; c < NCH; ++c) h += hp[(size_t)c * BH];
    const float h0 = fmaxf(h + b0v[n], 0.f);

    // ---- reduce z-GEMM split-K partials + weighted fusion ----
    const float y1 = Y1p[rn] + Y1p[BH + rn] + Y1p[2 * BH + rn] + Y1p[3 * BH + rn];
    float d = fmaf(fmaxf(y1 + b1v[n], 0.f), w1v[n], h0);
    const float y2 = Y2p[rn] + Y2p[BH + rn];
    d = fmaf(fmaxf(y2 + b2v[n], 0.f), w2v[n], d);
    const float y3 = Y3p[rn];
    d = fmaf(fmaxf(y3 + b3v[n], 0.f), w3v[n], d);

    // ---- tiny MLP 64->64->64->1 ----
    __shared__ float sd[4][64];
    __shared__ float sh[4][64];
    sd[w][n] = d;
    __syncthreads();
    float a1 = fb1[n];
    #pragma unroll 8
    for (int j = 0; j < 64; ++j) a1 = fmaf(sd[w][j], fW1[j * 64 + n], a1);
    a1 = fmaxf(a1, 0.f);
    sh[w][n] = a1;
    __syncthreads();
    float a2 = fb2[n];
    #pragma unroll 8
    for (int j = 0; j < 64; ++j) a2 = fmaf(sh[w][j], fW2[j * 64 + n], a2);
    a2 = fmaxf(a2, 0.f);

    float v = a2 * fW3[n];
    #pragma unroll
    for (int o = 32; o > 0; o >>= 1) v += __shfl_xor(v, o);
    if (n == 0) out[row] = v + fb3[0];
}

extern "C" void kernel_launch(void* const* d_in, const int* in_sizes, int n_in,
                              void* d_out, int out_size, void* d_ws, size_t ws_size,
                              hipStream_t stream)
{
    const float* x   = (const float*)d_in[0];
    const float* z1  = (const float*)d_in[1];
    const float* z2  = (const float*)d_in[2];
    const float* z3  = (const float*)d_in[3];
    const float* Wg  = (const float*)d_in[4];
    const float* bg  = (const float*)d_in[5];
    const float* W0  = (const float*)d_in[6];
    const float* b0v = (const float*)d_in[7];
    const float* W1  = (const float*)d_in[8];
    const float* b1v = (const float*)d_in[9];
    const float* W2  = (const float*)d_in[10];
    const float* b2v = (const float*)d_in[11];
    const float* W3  = (const float*)d_in[12];
    const float* b3v = (const float*)d_in[13];
    const float* w1v = (const float*)d_in[14];
    const float* w2v = (const float*)d_in[15];
    const float* w3v = (const float*)d_in[16];
    const float* fW1 = (const float*)d_in[17];
    const float* fb1 = (const float*)d_in[18];
    const float* fW2 = (const float*)d_in[19];
    const float* fb2 = (const float*)d_in[20];
    const float* fW3 = (const float*)d_in[21];
    const float* fb3 = (const float*)d_in[22];

    float* ws  = (float*)d_ws;
    float* out = (float*)d_out;

    k1_gene_fc0_zgemm<<<dim3(NGEMM_BLK + NGENE_BLK), dim3(256), 0, stream>>>(
        x, z1, z2, z3, Wg, bg, W0, W1, W2, W3, ws);

    k2_combine_mlp<<<dim3(BB / 4), dim3(256), 0, stream>>>(
        ws, b0v, b1v, b2v, b3v, w1v, w2v, w3v,
        fW1, fb1, fW2, fb2, fW3, fb3, out);
}